// Round 1
// baseline (592.180 us; speedup 1.0000x reference)
//
#include <hip/hip_runtime.h>
#include <cstdint>
#include <cstddef>

// BiARMA: N=50000 nodes, E=800000 edges, IN=64, HID=64, OUT=32, K=2 stacks, T=2 layers.
// Strategy:
//  - gcn_norm factored into dinv[src]*dinv[dst] pre/post scaling (no per-edge norm array)
//  - propagation commuted with weight GEMM: Agg(x W) = Agg(x) W -> propagate in the
//    smallest width, and share the t=0 aggregation across both stacks.
//  - CSR (counting sort by dst) built on-device each call -> atomic-free gather aggregation.
//  - per-node GEMMs: weights in LDS, activation row broadcast via v_readlane (SALU).

#define NN 50000
#define EE 800000

__device__ __forceinline__ float rl(float v, int l) {
  return __int_as_float(__builtin_amdgcn_readlane(__float_as_int(v), l));
}

// ---------------- CSR build ----------------

__global__ __launch_bounds__(256) void k_degree(const int* __restrict__ dst,
                                                int* __restrict__ deg) {
  int i = blockIdx.x * 256 + threadIdx.x;
  if (i < EE) atomicAdd(&deg[dst[i]], 1);
}

__global__ __launch_bounds__(1024) void k_scan(const int* __restrict__ deg,
                                               int* __restrict__ rowstart,
                                               float* __restrict__ dinv) {
  __shared__ int part[1024];
  const int T = 1024, C = (NN + T - 1) / T;  // 49 per thread
  int t = threadIdx.x;
  int base = t * C;
  int s = 0;
  for (int i = 0; i < C; i++) {
    int idx = base + i;
    if (idx < NN) s += deg[idx];
  }
  part[t] = s;
  __syncthreads();
  for (int off = 1; off < T; off <<= 1) {
    int v = (t >= off) ? part[t - off] : 0;
    __syncthreads();
    part[t] += v;
    __syncthreads();
  }
  int running = (t == 0) ? 0 : part[t - 1];
  for (int i = 0; i < C; i++) {
    int idx = base + i;
    if (idx < NN) {
      rowstart[idx] = running;
      int d = deg[idx];
      running += d;
      dinv[idx] = (d > 0) ? rsqrtf((float)d) : 0.f;
    }
  }
  if (t == T - 1) rowstart[NN] = running;
}

__global__ __launch_bounds__(256) void k_fill(const int* __restrict__ src,
                                              const int* __restrict__ dst,
                                              const int* __restrict__ rowstart,
                                              int* __restrict__ cursor,
                                              int* __restrict__ csr) {
  int i = blockIdx.x * 256 + threadIdx.x;
  if (i < EE) {
    int d = dst[i];
    int pos = rowstart[d] + atomicAdd(&cursor[d], 1);
    csr[pos] = src[i];
  }
}

// ---------------- elementwise scale (xs = x * dinv[n]) ----------------

__global__ __launch_bounds__(256) void k_scale(const float* __restrict__ x,
                                               const float* __restrict__ dinv,
                                               float* __restrict__ xs) {
  int i = blockIdx.x * 256 + threadIdx.x;  // over NN*16 float4s
  if (i < NN * 16) {
    int n = i >> 4;
    float d = dinv[n];
    float4 v = ((const float4*)x)[i];
    v.x *= d; v.y *= d; v.z *= d; v.w *= d;
    ((float4*)xs)[i] = v;
  }
}

// ---------------- CSR gather-aggregation, 64 floats/node ----------------
// one wave per node; lanes = 4 edge slots x 16 float4 columns

__global__ __launch_bounds__(256) void k_agg64(const float* __restrict__ in,
                                               const int* __restrict__ rowstart,
                                               const int* __restrict__ csr,
                                               float* __restrict__ out) {
  int wid = (blockIdx.x * 256 + threadIdx.x) >> 6;
  if (wid >= NN) return;
  int lane = threadIdx.x & 63;
  int f4 = lane & 15;
  int es = lane >> 4;
  int beg = rowstart[wid], end = rowstart[wid + 1];
  float4 acc = make_float4(0.f, 0.f, 0.f, 0.f);
  for (int j = beg + es; j < end; j += 4) {
    int s = csr[j];
    float4 v = ((const float4*)(in + (size_t)s * 64))[f4];
    acc.x += v.x; acc.y += v.y; acc.z += v.z; acc.w += v.w;
  }
#pragma unroll
  for (int off = 16; off < 64; off <<= 1) {
    acc.x += __shfl_xor(acc.x, off);
    acc.y += __shfl_xor(acc.y, off);
    acc.z += __shfl_xor(acc.z, off);
    acc.w += __shfl_xor(acc.w, off);
  }
  if (lane < 16) ((float4*)(out + (size_t)wid * 64))[f4] = acc;
}

// ---------------- ARMA1 t=0: root1 = x@rootW+b ; s = dinv*relu(dinv*aggx@initW + root1) ----

__global__ __launch_bounds__(256) void k_gemm1_t0(
    const float* __restrict__ x, const float* __restrict__ aggx,
    const float* __restrict__ dinv, const float* __restrict__ initW,
    const float* __restrict__ rootW, const float* __restrict__ bias,
    float* __restrict__ rootOut, float* __restrict__ sOut) {
  __shared__ float Wi[4096];
  __shared__ float Wr[4096];
  __shared__ float bs[64];
  for (int i = threadIdx.x; i < 4096; i += 256) { Wi[i] = initW[i]; Wr[i] = rootW[i]; }
  if (threadIdx.x < 64) bs[threadIdx.x] = bias[threadIdx.x];
  __syncthreads();
  int lane = threadIdx.x & 63;
  int wid = (blockIdx.x * 256 + threadIdx.x) >> 6;
  int nw = (gridDim.x * 256) >> 6;
  for (int n = wid; n < NN; n += nw) {
    float dn = dinv[n];
    float xv = x[(size_t)n * 64 + lane];
    float gv = aggx[(size_t)n * 64 + lane] * dn;
    float accR = bs[lane];
    float accI = 0.f;
#pragma unroll
    for (int c = 0; c < 64; c++) {
      accR = fmaf(rl(xv, c), Wr[c * 64 + lane], accR);
      accI = fmaf(rl(gv, c), Wi[c * 64 + lane], accI);
    }
    float o = fmaxf(accI + accR, 0.f);
    rootOut[(size_t)n * 64 + lane] = accR;
    sOut[(size_t)n * 64 + lane] = o * dn;
  }
}

// ---------------- ARMA1 t=1: o = relu(dinv*(agg@W) + root); h accumulate over stacks ----

template <int FINAL>
__global__ __launch_bounds__(256) void k_gemm1_t1(
    const float* __restrict__ agg, const float* __restrict__ root,
    const float* __restrict__ dinv, const float* __restrict__ W,
    float* __restrict__ hacc, float* __restrict__ hs) {
  __shared__ float Ws[4096];
  for (int i = threadIdx.x; i < 4096; i += 256) Ws[i] = W[i];
  __syncthreads();
  int lane = threadIdx.x & 63;
  int wid = (blockIdx.x * 256 + threadIdx.x) >> 6;
  int nw = (gridDim.x * 256) >> 6;
  for (int n = wid; n < NN; n += nw) {
    float dn = dinv[n];
    float av = agg[(size_t)n * 64 + lane];
    float acc = 0.f;
#pragma unroll
    for (int c = 0; c < 64; c++) acc = fmaf(rl(av, c), Ws[c * 64 + lane], acc);
    size_t idx = (size_t)n * 64 + lane;
    float o = fmaxf(fmaf(dn, acc, root[idx]), 0.f);
    if (FINAL) {
      float h = hacc[idx] + 0.5f * o;  // mean over K=2 stacks; outer relu is identity (o>=0)
      hacc[idx] = h;
      hs[idx] = h * dn;
    } else {
      hacc[idx] = 0.5f * o;
    }
  }
}

// ---------------- ARMA2 t=0 (both stacks in one wave: lane = k*32+col) ----------------

__global__ __launch_bounds__(256) void k_gemm2_t0(
    const float* __restrict__ h, const float* __restrict__ aggh,
    const float* __restrict__ dinv, const float* __restrict__ initW2,
    const float* __restrict__ rootW2, const float* __restrict__ b2,
    float* __restrict__ root2, float* __restrict__ s2) {
  __shared__ float Wi[4096];  // [k][c][col] = [2][64][32]
  __shared__ float Wr[4096];
  __shared__ float bs[64];
  for (int i = threadIdx.x; i < 4096; i += 256) { Wi[i] = initW2[i]; Wr[i] = rootW2[i]; }
  if (threadIdx.x < 64) bs[threadIdx.x] = b2[threadIdx.x];
  __syncthreads();
  int lane = threadIdx.x & 63;
  int k = lane >> 5, col = lane & 31;
  int wid = (blockIdx.x * 256 + threadIdx.x) >> 6;
  int nw = (gridDim.x * 256) >> 6;
  for (int n = wid; n < NN; n += nw) {
    float dn = dinv[n];
    float hv = h[(size_t)n * 64 + lane];
    float gv = aggh[(size_t)n * 64 + lane] * dn;
    float accR = bs[lane];
    float accI = 0.f;
#pragma unroll
    for (int c = 0; c < 64; c++) {
      accR = fmaf(rl(hv, c), Wr[(k * 64 + c) * 32 + col], accR);
      accI = fmaf(rl(gv, c), Wi[(k * 64 + c) * 32 + col], accI);
    }
    float o = fmaxf(accI + accR, 0.f);
    root2[(size_t)n * 64 + lane] = accR;
    s2[(size_t)n * 64 + lane] = o * dn;
  }
}

// ---------------- ARMA2 t=1 + mean over stacks -> d_out ----------------

__global__ __launch_bounds__(256) void k_gemm2_t1(
    const float* __restrict__ agg2, const float* __restrict__ root2,
    const float* __restrict__ dinv, const float* __restrict__ W2,
    float* __restrict__ outp) {
  __shared__ float Ws[2048];  // [2][32][32]
  for (int i = threadIdx.x; i < 2048; i += 256) Ws[i] = W2[i];
  __syncthreads();
  int lane = threadIdx.x & 63;
  int k = lane >> 5, col = lane & 31;
  int wid = (blockIdx.x * 256 + threadIdx.x) >> 6;
  int nw = (gridDim.x * 256) >> 6;
  for (int n = wid; n < NN; n += nw) {
    float dn = dinv[n];
    float av = agg2[(size_t)n * 64 + lane];
    float acc = 0.f;
#pragma unroll
    for (int c = 0; c < 32; c++) {
      float a0 = rl(av, c), a1 = rl(av, 32 + c);
      float ac = (lane < 32) ? a0 : a1;
      acc = fmaf(ac, Ws[(k * 32 + c) * 32 + col], acc);
    }
    float o = fmaxf(fmaf(dn, acc, root2[(size_t)n * 64 + lane]), 0.f);
    o += __shfl_xor(o, 32);
    if (lane < 32) outp[(size_t)n * 32 + col] = 0.5f * o;
  }
}

// ---------------- host launch ----------------

extern "C" void kernel_launch(void* const* d_in, const int* in_sizes, int n_in,
                              void* d_out, int out_size, void* d_ws, size_t ws_size,
                              hipStream_t stream) {
  const float* x = (const float*)d_in[0];
  const int* edge_index = (const int*)d_in[1];
  const float* initW1 = (const float*)d_in[2];   // [2][64][64]
  const float* w1 = (const float*)d_in[3];       // [1][2][64][64]
  const float* rootW1 = (const float*)d_in[4];   // [1][2][64][64]
  const float* b1 = (const float*)d_in[5];       // [1][2][1][64]
  const float* initW2 = (const float*)d_in[6];   // [2][64][32]
  const float* w2 = (const float*)d_in[7];       // [1][2][32][32]
  const float* rootW2 = (const float*)d_in[8];   // [1][2][64][32]
  const float* b2 = (const float*)d_in[9];       // [1][2][1][32]
  float* out = (float*)d_out;

  const int* src = edge_index;
  const int* dst = edge_index + EE;

  // workspace carve-up (256B aligned)
  size_t off = 0;
  auto carve = [&](size_t bytes) {
    size_t r = off;
    off = (off + bytes + 255) & ~(size_t)255;
    return r;
  };
  char* ws = (char*)d_ws;
  int* deg = (int*)(ws + carve((size_t)NN * 4));
  int* cursor = (int*)(ws + carve((size_t)NN * 4));
  int* rowstart = (int*)(ws + carve((size_t)(NN + 1) * 4));
  int* csr = (int*)(ws + carve((size_t)EE * 4));
  float* dinv = (float*)(ws + carve((size_t)NN * 4));
  float* B_aggx = (float*)(ws + carve((size_t)NN * 64 * 4));  // agg_x / agg_h
  float* B_root = (float*)(ws + carve((size_t)NN * 64 * 4));  // root1(k) / root2(both)
  float* B_s = (float*)(ws + carve((size_t)NN * 64 * 4));     // xs / s1(k) / hs / s2
  float* B_agg = (float*)(ws + carve((size_t)NN * 64 * 4));   // agg of s
  float* B_h = (float*)(ws + carve((size_t)NN * 64 * 4));     // h accumulator
  (void)ws_size; (void)in_sizes; (void)n_in; (void)out_size;

  const int EB = (EE + 255) / 256;
  const int AGGB = (NN + 3) / 4;
  const int GB = 1024;  // GEMM blocks (4 waves each)

  hipMemsetAsync(deg, 0, (size_t)NN * 4, stream);
  hipMemsetAsync(cursor, 0, (size_t)NN * 4, stream);
  k_degree<<<EB, 256, 0, stream>>>(dst, deg);
  k_scan<<<1, 1024, 0, stream>>>(deg, rowstart, dinv);
  k_fill<<<EB, 256, 0, stream>>>(src, dst, rowstart, cursor, csr);

  // ----- ARMA1 -----
  k_scale<<<(NN * 16 + 255) / 256, 256, 0, stream>>>(x, dinv, B_s);
  k_agg64<<<AGGB, 256, 0, stream>>>(B_s, rowstart, csr, B_aggx);
  // k = 0
  k_gemm1_t0<<<GB, 256, 0, stream>>>(x, B_aggx, dinv, initW1, rootW1, b1, B_root, B_s);
  k_agg64<<<AGGB, 256, 0, stream>>>(B_s, rowstart, csr, B_agg);
  k_gemm1_t1<0><<<GB, 256, 0, stream>>>(B_agg, B_root, dinv, w1, B_h, nullptr);
  // k = 1
  k_gemm1_t0<<<GB, 256, 0, stream>>>(x, B_aggx, dinv, initW1 + 4096, rootW1 + 4096,
                                     b1 + 64, B_root, B_s);
  k_agg64<<<AGGB, 256, 0, stream>>>(B_s, rowstart, csr, B_agg);
  k_gemm1_t1<1><<<GB, 256, 0, stream>>>(B_agg, B_root, dinv, w1 + 4096, B_h, B_s);

  // ----- ARMA2 ----- (B_s now holds hs = h*dinv)
  k_agg64<<<AGGB, 256, 0, stream>>>(B_s, rowstart, csr, B_aggx);
  k_gemm2_t0<<<GB, 256, 0, stream>>>(B_h, B_aggx, dinv, initW2, rootW2, b2, B_root, B_s);
  k_agg64<<<AGGB, 256, 0, stream>>>(B_s, rowstart, csr, B_agg);
  k_gemm2_t1<<<GB, 256, 0, stream>>>(B_agg, B_root, dinv, w2, out);
}

// Round 2
// 536.311 us; speedup vs baseline: 1.1042x; 1.1042x over previous
//
#include <hip/hip_runtime.h>
#include <cstdint>
#include <cstddef>

// BiARMA: N=50000, E=800000, IN=64, HID=64, OUT=32, K=2 stacks, T=2 layers.
//  - gcn_norm factored into dinv pre/post scaling (no per-edge norm array)
//  - Agg(xW) = Agg(x)W: propagate in width-64 always; stacks packed/merged
//  - CSR built on-device (parallel 3-kernel scan), atomic-free gathers
//  - agg fused into consuming GEMM where exclusive; shfl-based wave transpose
//  - per-node GEMMs: weights in LDS, activation row broadcast via v_readlane

#define NN 50000
#define EE 800000
#define NCHUNK ((NN + 255) / 256)  // 196

__device__ __forceinline__ float rl(float v, int l) {
  return __int_as_float(__builtin_amdgcn_readlane(__float_as_int(v), l));
}

// butterfly: after this, every lane holds the full sum for its f4 = lane&15
__device__ __forceinline__ void red4(float4& a) {
#pragma unroll
  for (int off = 16; off < 64; off <<= 1) {
    a.x += __shfl_xor(a.x, off);
    a.y += __shfl_xor(a.y, off);
    a.z += __shfl_xor(a.z, off);
    a.w += __shfl_xor(a.w, off);
  }
}

// lane l gets feature l (float4-per-16-lane layout -> scalar-per-lane layout)
__device__ __forceinline__ float transp(float4 a, int lane) {
  int s = lane >> 2;
  float b0 = __shfl(a.x, s), b1 = __shfl(a.y, s), b2 = __shfl(a.z, s), b3 = __shfl(a.w, s);
  int c = lane & 3;
  return (c == 0) ? b0 : (c == 1) ? b1 : (c == 2) ? b2 : b3;
}

// ---------------- CSR build ----------------

__global__ __launch_bounds__(256) void k_degree(const int* __restrict__ dst,
                                                int* __restrict__ deg) {
  int i = blockIdx.x * 256 + threadIdx.x;
  if (i < EE) atomicAdd(&deg[dst[i]], 1);
}

__global__ __launch_bounds__(256) void k_part(const int* __restrict__ deg,
                                              int* __restrict__ partial) {
  int i = blockIdx.x * 256 + threadIdx.x;
  int v = (i < NN) ? deg[i] : 0;
#pragma unroll
  for (int off = 1; off < 64; off <<= 1) v += __shfl_xor(v, off);
  __shared__ int wsum[4];
  if ((threadIdx.x & 63) == 0) wsum[threadIdx.x >> 6] = v;
  __syncthreads();
  if (threadIdx.x == 0) partial[blockIdx.x] = wsum[0] + wsum[1] + wsum[2] + wsum[3];
}

__global__ __launch_bounds__(256) void k_scanp(const int* __restrict__ partial,
                                               int* __restrict__ chunkbase) {
  __shared__ int sc[256];
  int t = threadIdx.x;
  int v = (t < NCHUNK) ? partial[t] : 0;
  sc[t] = v;
  __syncthreads();
  for (int off = 1; off < 256; off <<= 1) {
    int u = (t >= off) ? sc[t - off] : 0;
    __syncthreads();
    sc[t] += u;
    __syncthreads();
  }
  if (t < NCHUNK) chunkbase[t] = sc[t] - v;  // exclusive
}

__global__ __launch_bounds__(256) void k_rows(const int* __restrict__ deg,
                                              const int* __restrict__ chunkbase,
                                              int* __restrict__ rowstart,
                                              float* __restrict__ dinv,
                                              int* __restrict__ cursor) {
  __shared__ int sc[256];
  int t = threadIdx.x;
  int i = blockIdx.x * 256 + t;
  int d = (i < NN) ? deg[i] : 0;
  sc[t] = d;
  __syncthreads();
  for (int off = 1; off < 256; off <<= 1) {
    int u = (t >= off) ? sc[t - off] : 0;
    __syncthreads();
    sc[t] += u;
    __syncthreads();
  }
  if (i < NN) {
    rowstart[i] = chunkbase[blockIdx.x] + sc[t] - d;
    dinv[i] = (d > 0) ? rsqrtf((float)d) : 0.f;
    cursor[i] = 0;
  }
  if (blockIdx.x == 0 && t == 0) rowstart[NN] = EE;
}

__global__ __launch_bounds__(256) void k_fill(const int* __restrict__ src,
                                              const int* __restrict__ dst,
                                              const int* __restrict__ rowstart,
                                              int* __restrict__ cursor,
                                              int* __restrict__ csr) {
  int i = blockIdx.x * 256 + threadIdx.x;
  if (i < EE) {
    int d = dst[i];
    int pos = rowstart[d] + atomicAdd(&cursor[d], 1);
    csr[pos] = src[i];
  }
}

// ---------------- agg(x*dinv[s]) * dinv[n] -> aggxs [N,64] ----------------

__global__ __launch_bounds__(256) void k_aggx(const float* __restrict__ x,
                                              const float* __restrict__ dinv,
                                              const int* __restrict__ rowstart,
                                              const int* __restrict__ csr,
                                              float* __restrict__ outp) {
  int wid = (blockIdx.x * 256 + threadIdx.x) >> 6;
  if (wid >= NN) return;
  int lane = threadIdx.x & 63;
  int f4 = lane & 15, es = lane >> 4;
  int beg = rowstart[wid], end = rowstart[wid + 1];
  float4 acc = {0.f, 0.f, 0.f, 0.f};
  const float4* x4 = (const float4*)x;
  for (int j = beg + es; j < end; j += 4) {
    int s = csr[j];
    float ds = dinv[s];
    float4 v = x4[(size_t)s * 16 + f4];
    acc.x = fmaf(v.x, ds, acc.x);
    acc.y = fmaf(v.y, ds, acc.y);
    acc.z = fmaf(v.z, ds, acc.z);
    acc.w = fmaf(v.w, ds, acc.w);
  }
  red4(acc);
  if (lane < 16) {
    float dn = dinv[wid];
    acc.x *= dn; acc.y *= dn; acc.z *= dn; acc.w *= dn;
    ((float4*)outp)[(size_t)wid * 16 + f4] = acc;
  }
}

// ---------------- ARMA1 t=0, both stacks ----------------
// root_k = x@Wr_k + b_k ; s_k = dinv * relu(aggxs@Wi_k + root_k)

__global__ __launch_bounds__(256) void k_t0(const float* __restrict__ x,
                                            const float* __restrict__ aggxs,
                                            const float* __restrict__ initW,
                                            const float* __restrict__ rootW,
                                            const float* __restrict__ bias,
                                            const float* __restrict__ dinv,
                                            float* __restrict__ root01,
                                            float* __restrict__ s01) {
  __shared__ float Wi[8192];
  __shared__ float Wr[8192];
  __shared__ float bs[128];
  for (int i = threadIdx.x; i < 8192; i += 256) { Wi[i] = initW[i]; Wr[i] = rootW[i]; }
  if (threadIdx.x < 128) bs[threadIdx.x] = bias[threadIdx.x];
  __syncthreads();
  int lane = threadIdx.x & 63;
  int wid = (blockIdx.x * 256 + threadIdx.x) >> 6;
  int nw = (gridDim.x * 256) >> 6;
  for (int n = wid; n < NN; n += nw) {
    float dn = dinv[n];
    float xv = x[(size_t)n * 64 + lane];
    float gv = aggxs[(size_t)n * 64 + lane];
    float r0 = bs[lane], r1 = bs[64 + lane];
    float i0 = 0.f, i1 = 0.f;
#pragma unroll
    for (int c = 0; c < 64; c++) {
      float xc = rl(xv, c), gc = rl(gv, c);
      r0 = fmaf(xc, Wr[c * 64 + lane], r0);
      r1 = fmaf(xc, Wr[4096 + c * 64 + lane], r1);
      i0 = fmaf(gc, Wi[c * 64 + lane], i0);
      i1 = fmaf(gc, Wi[4096 + c * 64 + lane], i1);
    }
    size_t b = (size_t)n * 128 + lane;
    root01[b] = r0;
    root01[b + 64] = r1;
    s01[b] = fmaxf(i0 + r0, 0.f) * dn;
    s01[b + 64] = fmaxf(i1 + r1, 0.f) * dn;
  }
}

// ---------------- ARMA1 t=1 fused: gather s0,s1 + GEMM + h ----------------

__global__ __launch_bounds__(256) void k_t1(const float* __restrict__ s01,
                                            const float* __restrict__ root01,
                                            const float* __restrict__ W,
                                            const float* __restrict__ dinv,
                                            const int* __restrict__ rowstart,
                                            const int* __restrict__ csr,
                                            float* __restrict__ h,
                                            float* __restrict__ hs) {
  __shared__ float Ws[8192];
  for (int i = threadIdx.x; i < 8192; i += 256) Ws[i] = W[i];
  __syncthreads();
  int lane = threadIdx.x & 63;
  int f4 = lane & 15, es = lane >> 4;
  int wid = (blockIdx.x * 256 + threadIdx.x) >> 6;
  int nw = (gridDim.x * 256) >> 6;
  const float4* in4 = (const float4*)s01;
  for (int n = wid; n < NN; n += nw) {
    int beg = rowstart[n], end = rowstart[n + 1];
    float4 a0 = {0.f, 0.f, 0.f, 0.f}, a1 = {0.f, 0.f, 0.f, 0.f};
    for (int j = beg + es; j < end; j += 4) {
      int s = csr[j];
      const float4* r = in4 + (size_t)s * 32;
      float4 v0 = r[f4], v1 = r[16 + f4];
      a0.x += v0.x; a0.y += v0.y; a0.z += v0.z; a0.w += v0.w;
      a1.x += v1.x; a1.y += v1.y; a1.z += v1.z; a1.w += v1.w;
    }
    red4(a0);
    red4(a1);
    float av0 = transp(a0, lane);
    float av1 = transp(a1, lane);
    float dn = dinv[n];
    float c0 = 0.f, c1 = 0.f;
#pragma unroll
    for (int c = 0; c < 64; c++) {
      c0 = fmaf(rl(av0, c), Ws[c * 64 + lane], c0);
      c1 = fmaf(rl(av1, c), Ws[4096 + c * 64 + lane], c1);
    }
    size_t b = (size_t)n * 128 + lane;
    float o0 = fmaxf(fmaf(dn, c0, root01[b]), 0.f);
    float o1 = fmaxf(fmaf(dn, c1, root01[b + 64]), 0.f);
    float hv = 0.5f * (o0 + o1);
    h[(size_t)n * 64 + lane] = hv;
    hs[(size_t)n * 64 + lane] = hv * dn;
  }
}

// ---------------- ARMA2 t=0 fused: gather hs + GEMM (stacks packed) ----------------

__global__ __launch_bounds__(256) void k2_t0(const float* __restrict__ h,
                                             const float* __restrict__ hs,
                                             const float* __restrict__ initW2,
                                             const float* __restrict__ rootW2,
                                             const float* __restrict__ b2,
                                             const float* __restrict__ dinv,
                                             const int* __restrict__ rowstart,
                                             const int* __restrict__ csr,
                                             float* __restrict__ root2,
                                             float* __restrict__ s2) {
  __shared__ float Wi[4096];
  __shared__ float Wr[4096];
  __shared__ float bs[64];
  for (int i = threadIdx.x; i < 4096; i += 256) { Wi[i] = initW2[i]; Wr[i] = rootW2[i]; }
  if (threadIdx.x < 64) bs[threadIdx.x] = b2[threadIdx.x];
  __syncthreads();
  int lane = threadIdx.x & 63;
  int f4 = lane & 15, es = lane >> 4;
  int k = lane >> 5, col = lane & 31;
  int wid = (blockIdx.x * 256 + threadIdx.x) >> 6;
  int nw = (gridDim.x * 256) >> 6;
  const float4* in4 = (const float4*)hs;
  for (int n = wid; n < NN; n += nw) {
    int beg = rowstart[n], end = rowstart[n + 1];
    float4 a = {0.f, 0.f, 0.f, 0.f};
    for (int j = beg + es; j < end; j += 4) {
      int s = csr[j];
      float4 v = in4[(size_t)s * 16 + f4];
      a.x += v.x; a.y += v.y; a.z += v.z; a.w += v.w;
    }
    red4(a);
    float dn = dinv[n];
    float av = transp(a, lane) * dn;      // dinv[n] * Agg(hs), feature `lane`
    float hv = h[(size_t)n * 64 + lane];  // feature `lane` of h
    float accR = bs[lane];
    float accI = 0.f;
#pragma unroll
    for (int c = 0; c < 64; c++) {
      float xc = rl(hv, c), gc = rl(av, c);
      accR = fmaf(xc, Wr[k * 2048 + c * 32 + col], accR);
      accI = fmaf(gc, Wi[k * 2048 + c * 32 + col], accI);
    }
    float o = fmaxf(accI + accR, 0.f);
    root2[(size_t)n * 64 + lane] = accR;
    s2[(size_t)n * 64 + lane] = o * dn;
  }
}

// ---------------- ARMA2 t=1 fused: gather s2 + GEMM + mean -> out ----------------

__global__ __launch_bounds__(256) void k2_t1(const float* __restrict__ s2,
                                             const float* __restrict__ root2,
                                             const float* __restrict__ W2,
                                             const float* __restrict__ dinv,
                                             const int* __restrict__ rowstart,
                                             const int* __restrict__ csr,
                                             float* __restrict__ outp) {
  __shared__ float Ws[2048];
  for (int i = threadIdx.x; i < 2048; i += 256) Ws[i] = W2[i];
  __syncthreads();
  int lane = threadIdx.x & 63;
  int f4 = lane & 15, es = lane >> 4;
  int k = lane >> 5, col = lane & 31;
  int wid = (blockIdx.x * 256 + threadIdx.x) >> 6;
  int nw = (gridDim.x * 256) >> 6;
  const float4* in4 = (const float4*)s2;
  for (int n = wid; n < NN; n += nw) {
    int beg = rowstart[n], end = rowstart[n + 1];
    float4 a = {0.f, 0.f, 0.f, 0.f};
    for (int j = beg + es; j < end; j += 4) {
      int s = csr[j];
      float4 v = in4[(size_t)s * 16 + f4];
      a.x += v.x; a.y += v.y; a.z += v.z; a.w += v.w;
    }
    red4(a);
    float dn = dinv[n];
    float av = transp(a, lane) * dn;  // dinv[n]*Agg(s2), packed feature `lane`
    float acc = 0.f;
#pragma unroll
    for (int c = 0; c < 32; c++) {
      float p0 = rl(av, c), p1 = rl(av, 32 + c);
      float pc = (lane < 32) ? p0 : p1;
      acc = fmaf(pc, Ws[k * 1024 + c * 32 + col], acc);
    }
    float o = fmaxf(acc + root2[(size_t)n * 64 + lane], 0.f);
    o += __shfl_xor(o, 32);
    if (lane < 32) outp[(size_t)n * 32 + col] = 0.5f * o;
  }
}

// ---------------- host launch ----------------

extern "C" void kernel_launch(void* const* d_in, const int* in_sizes, int n_in,
                              void* d_out, int out_size, void* d_ws, size_t ws_size,
                              hipStream_t stream) {
  const float* x = (const float*)d_in[0];
  const int* edge_index = (const int*)d_in[1];
  const float* initW1 = (const float*)d_in[2];
  const float* w1 = (const float*)d_in[3];
  const float* rootW1 = (const float*)d_in[4];
  const float* b1 = (const float*)d_in[5];
  const float* initW2 = (const float*)d_in[6];
  const float* w2 = (const float*)d_in[7];
  const float* rootW2 = (const float*)d_in[8];
  const float* b2 = (const float*)d_in[9];
  float* out = (float*)d_out;

  const int* src = edge_index;
  const int* dst = edge_index + EE;

  size_t off = 0;
  auto carve = [&](size_t bytes) {
    size_t r = off;
    off = (off + bytes + 255) & ~(size_t)255;
    return r;
  };
  char* ws = (char*)d_ws;
  int* deg = (int*)(ws + carve((size_t)NN * 4));
  int* rowstart = (int*)(ws + carve((size_t)(NN + 1) * 4));
  int* csr = (int*)(ws + carve((size_t)EE * 4));
  float* dinv = (float*)(ws + carve((size_t)NN * 4));
  int* cursor = (int*)(ws + carve((size_t)NN * 4));
  int* partial = (int*)(ws + carve(256 * 4));
  int* chunkbase = (int*)(ws + carve(256 * 4));
  float* B1 = (float*)(ws + carve((size_t)NN * 64 * 4));   // aggxs, later h
  float* B2 = (float*)(ws + carve((size_t)NN * 128 * 4));  // root01, later root2
  float* B3 = (float*)(ws + carve((size_t)NN * 128 * 4));  // s01, later s2
  float* B4 = (float*)(ws + carve((size_t)NN * 64 * 4));   // hs
  (void)ws_size; (void)in_sizes; (void)n_in; (void)out_size;

  const int EB = (EE + 255) / 256;
  const int AGGB = (NN + 3) / 4;

  hipMemsetAsync(deg, 0, (size_t)NN * 4, stream);
  k_degree<<<EB, 256, 0, stream>>>(dst, deg);
  k_part<<<NCHUNK, 256, 0, stream>>>(deg, partial);
  k_scanp<<<1, 256, 0, stream>>>(partial, chunkbase);
  k_rows<<<NCHUNK, 256, 0, stream>>>(deg, chunkbase, rowstart, dinv, cursor);
  k_fill<<<EB, 256, 0, stream>>>(src, dst, rowstart, cursor, csr);

  k_aggx<<<AGGB, 256, 0, stream>>>(x, dinv, rowstart, csr, B1);
  k_t0<<<512, 256, 0, stream>>>(x, B1, initW1, rootW1, b1, dinv, B2, B3);
  k_t1<<<1024, 256, 0, stream>>>(B3, B2, w1, dinv, rowstart, csr, B1, B4);
  k2_t0<<<1024, 256, 0, stream>>>(B1, B4, initW2, rootW2, b2, dinv, rowstart, csr, B2, B3);
  k2_t1<<<1024, 256, 0, stream>>>(B3, B2, w2, dinv, rowstart, csr, out);
}